// Round 12
// baseline (443.826 us; speedup 1.0000x reference)
//
#include <hip/hip_runtime.h>

#define EPS 1e-5f
typedef unsigned short u16;
typedef __attribute__((ext_vector_type(8))) short short8;
typedef __attribute__((ext_vector_type(4))) float f32x4;

__device__ __forceinline__ float bf2f(u16 u) {
  union { unsigned int i; float f; } c; c.i = ((unsigned int)u) << 16; return c.f;
}
__device__ __forceinline__ u16 f2bf(float f) {
  union { float f; unsigned int i; } c; c.f = f;
  unsigned int u = c.i;
  u += 0x7fffu + ((u >> 16) & 1u);   // round-to-nearest-even
  return (u16)(u >> 16);
}
__device__ __forceinline__ unsigned int cvt_pk_bf16(float lo, float hi) {
  unsigned int r;
  asm("v_cvt_pk_bf16_f32 %0, %1, %2" : "=v"(r) : "v"(lo), "v"(hi));
  return r;
}
// unaligned-safe 16B load (H rows are 50B-strided)
__device__ __forceinline__ short8 load8u(const u16* p) {
  short8 v; __builtin_memcpy(&v, p, 16); return v;
}
// async global->LDS, 16B per lane; dest = wave-uniform base + lane*16 (linear)
__device__ __forceinline__ void gload16(const u16* g, u16* l) {
  __builtin_amdgcn_global_load_lds(
      (__attribute__((address_space(1))) void*)(void*)g,
      (__attribute__((address_space(3))) void*)l, 16, 0, 0);
}

// ---------- merged prep: 6 weight transposes, ATb, Hct end-pad ----------
__device__ __forceinline__ void prep_w_elem(const float* W, u16* Wt,
    int cin, int cout, int P, int idx) {
  const int K = P*cin;
  const int co = idx / K, k = idx % K;
  const int p = k / cin, ci = k % cin;
  Wt[idx] = f2bf(W[((size_t)(p*cout + co))*cin + ci]);
}

__global__ __launch_bounds__(256) void k_prep_all(
    const float* __restrict__ A,
    const float* __restrict__ i0, const float* __restrict__ i1,
    const float* __restrict__ i2, const float* __restrict__ i3,
    const float* __restrict__ W0, const float* __restrict__ W1,
    const float* __restrict__ Wr1, const float* __restrict__ W2,
    const float* __restrict__ Wr2, const float* __restrict__ W3,
    u16* W0t, u16* W1t, u16* Wr1t, u16* W2t,
    u16* Wr2t, u16* W3t, u16* ATb, u16* hpad) {
  int idx = blockIdx.x*256 + threadIdx.x;
  if (idx < 12288) { prep_w_elem(W0,  W0t,  64,  64,  3, idx); return; }
  idx -= 12288;
  if (idx < 24576) { prep_w_elem(W1,  W1t,  64,  128, 3, idx); return; }
  idx -= 24576;
  if (idx < 8192)  { prep_w_elem(Wr1, Wr1t, 64,  128, 1, idx); return; }
  idx -= 8192;
  if (idx < 98304) { prep_w_elem(W2,  W2t,  128, 256, 3, idx); return; }
  idx -= 98304;
  if (idx < 32768) { prep_w_elem(Wr2, Wr2t, 128, 256, 1, idx); return; }
  idx -= 32768;
  if (idx < 196608){ prep_w_elem(W3,  W3t,  256, 256, 3, idx); return; }
  idx -= 196608;
  if (idx < 12288) {                     // ATb[l][p][w(32)][v(32)] = bf16(A'[p][v][w]), zero-padded
    const int l = idx / 3072, r = idx % 3072;
    const int p = r / 1024, wv = r % 1024;
    const int w = wv >> 5, v = wv & 31;
    float val = 0.f;
    if (w < 25 && v < 25) {
      const float* imp = (l==0)?i0:(l==1)?i1:(l==2)?i2:i3;
      val = A[(p*25 + v)*25 + w] * imp[v*25 + w];
    }
    ATb[idx] = f2bf(val);
    return;
  }
  idx -= 12288;
  if (idx < 32) hpad[idx] = 0;           // safe overhang for xa_mfma A-frags
}

// ---------- input BN stats: per j = v*3+c over (n,t) ----------
__global__ __launch_bounds__(256) void k_bn_in_stats(const float* __restrict__ x,
    const float* __restrict__ g, const float* __restrict__ b,
    float* __restrict__ iscale, float* __restrict__ ishift) {
  const int j = blockIdx.x;            // 0..74
  const int c = j % 3, v = j / 3;
  const int tid = threadIdx.x;
  float s = 0.f, q = 0.f;
  for (int i = tid; i < 2400; i += 256) {
    const int n = i / 300, t = i % 300;
    const float val = x[(((size_t)n*3 + c)*300 + t)*25 + v];
    s += val; q += val*val;
  }
  __shared__ float rs[256], rq[256];
  rs[tid] = s; rq[tid] = q;
  __syncthreads();
  for (int off = 128; off > 0; off >>= 1) {
    if (tid < off) { rs[tid] += rs[tid+off]; rq[tid] += rq[tid+off]; }
    __syncthreads();
  }
  if (tid == 0) {
    const float mean = rs[0] / 2400.f;
    const float var  = rq[0] / 2400.f - mean*mean;
    const float sc = g[j] * rsqrtf(var + EPS);
    iscale[j] = sc;
    ishift[j] = b[j] - mean*sc;
  }
}

// ---------- fused input-BN apply + fin (3 -> 64), writes bf16 H_ct ----------
__global__ __launch_bounds__(256) void k_fin(const float* __restrict__ x,
    const float* __restrict__ iscale, const float* __restrict__ ishift,
    const float* __restrict__ fW, const float* __restrict__ fb,
    u16* __restrict__ H) {
  const int n = blockIdx.y;
  const int t0 = blockIdx.x * 10;
  const int tid = threadIdx.x;
  __shared__ float xn[3][250];
  __shared__ float wsh[64][3];
  __shared__ float bsh[64];
  if (tid < 192) wsh[tid/3][tid%3] = fW[tid];
  if (tid < 64)  bsh[tid] = fb[tid];
  for (int i = tid; i < 750; i += 256) {
    const int c = i / 250, pos = i % 250;
    const int t = t0 + pos/25, v = pos%25;
    const int j = v*3 + c;
    xn[c][pos] = x[(((size_t)n*3 + c)*300 + t)*25 + v] * iscale[j] + ishift[j];
  }
  __syncthreads();
  for (int e = tid; e < 64*250; e += 256) {
    const int o = e / 250, pos = e % 250;
    float acc = bsh[o]
              + xn[0][pos]*wsh[o][0] + xn[1][pos]*wsh[o][1] + xn[2][pos]*wsh[o][2];
    const int t = t0 + pos/25, v = pos%25;
    H[(((size_t)n*64 + o)*300 + t)*25 + v] = f2bf(acc);
  }
}

// ---------- Hmk transpose: Hmk[(n*7500+m)][ci] = H[n][ci][m] ----------
__global__ __launch_bounds__(256) void k_hmk(const u16* __restrict__ H,
    u16* __restrict__ Hmk, int cin) {
  const int m0  = blockIdx.x * 64;
  const int ci0 = blockIdx.y * 32;
  const int n   = blockIdx.z;
  __shared__ u16 tile[32][72];
  const int tid = threadIdx.x;
  {
    const int ci = tid >> 3, chunk = tid & 7;
    const int m = m0 + chunk * 8;
    const u16* src = &H[(size_t)(n*cin + ci0 + ci)*7500];
    short8 v;
    if (m + 7 < 7500) {
      v = load8u(&src[m]);
    } else {
      #pragma unroll
      for (int j = 0; j < 8; ++j)
        ((u16*)&v)[j] = (m + j < 7500) ? src[m + j] : (u16)0;
    }
    *(short8*)&tile[ci][chunk*8] = v;
  }
  __syncthreads();
  const int mr = tid >> 2, cq = (tid & 3) * 8;
  const int m = m0 + mr;
  if (m < 7500) {
    short8 v;
    #pragma unroll
    for (int j = 0; j < 8; ++j) ((u16*)&v)[j] = tile[cq + j][mr];
    *(short8*)&Hmk[((size_t)n*7500 + m)*cin + ci0 + cq] = v;
  }
}

// ---------- xa via MFMA v5: r8 operand order (packed b64 LDS writes), ----------
// 2 timesteps sequentially (halved LDS), coalesced copy-out.
// D = mfma(af, bf): row=ci, col=w -> each lane packs 4 consecutive ci for one w
// into a single ds_write_b64 (vs 4 scalar b16 in v4).
template<int CIN>
__global__ __launch_bounds__(256) void k_xa_mfma5(const u16* __restrict__ H,
    const u16* __restrict__ ATl, u16* __restrict__ XA) {
  constexpr int K = 3 * CIN;
  constexpr int ldz = K + 8;
  constexpr int ncit = CIN >> 4;
  constexpr int rowchunks = K >> 3;
  const int t0 = blockIdx.x * 2, n = blockIdx.y;
  const int tid = threadIdx.x, lane = tid & 63, wid = tid >> 6;
  const int lrow = lane & 15, lchunk = lane >> 4;
  extern __shared__ u16 zt[];              // [25][K+8]

  short8 bf[3][2];
  #pragma unroll
  for (int p = 0; p < 3; ++p)
    #pragma unroll
    for (int wt = 0; wt < 2; ++wt)
      bf[p][wt] = *(const short8*)&ATl[(p*32 + wt*16 + lrow)*32 + lchunk*8];

  const int w0 = lrow;                     // D col = lane&15
  const int ciq = lchunk * 4;              // D rows = (lane>>4)*4 + r

  #pragma unroll
  for (int tl = 0; tl < 2; ++tl) {
    const int t = t0 + tl;
    if (tl) __syncthreads();               // previous copy-out complete
    for (int citile = wid; citile < ncit; citile += 4) {
      const int ci = citile*16 + lrow;
      const short8 af = load8u(&H[((size_t)(n*CIN + ci)*300 + t)*25 + lchunk*8]);
      #pragma unroll
      for (int p = 0; p < 3; ++p) {
        #pragma unroll
        for (int wt = 0; wt < 2; ++wt) {
          f32x4 acc = (f32x4){0.f, 0.f, 0.f, 0.f};
          acc = __builtin_amdgcn_mfma_f32_16x16x32_bf16(af, bf[p][wt], acc, 0, 0, 0);
          const int w = wt*16 + w0;
          if (w < 25) {
            uint2 pk;
            pk.x = cvt_pk_bf16(acc[0], acc[1]);
            pk.y = cvt_pk_bf16(acc[2], acc[3]);
            *(uint2*)&zt[w*ldz + p*CIN + citile*16 + ciq] = pk;
          }
        }
      }
    }
    __syncthreads();
    const size_t mbase = ((size_t)n*300 + t)*25;
    for (int i = tid; i < 25*rowchunks; i += 256) {
      const int row = i / rowchunks, c = i % rowchunks;
      *(short8*)&XA[(mbase + row)*K + c*8] = *(const short8*)&zt[row*ldz + c*8];
    }
  }
}

// ---------- bf16 MFMA GEMM, 128x64 tile (N=64/128) ----------
__global__ __launch_bounds__(256) void k_gemm(const u16* __restrict__ Asrc,
    const u16* __restrict__ Bsrc, u16* __restrict__ Cb, int K) {
  const int n0b = blockIdx.x * 64;
  const int m0  = blockIdx.y * 128;
  const int tid = threadIdx.x;
  const int lane = tid & 63, wid = tid >> 6;
  const int wm = (wid & 1) * 64, wn = (wid >> 1) * 32;

  __shared__ u16 As[128*64];
  __shared__ u16 Bs[64*64];

  f32x4 acc[4][2];
  #pragma unroll
  for (int mi = 0; mi < 4; ++mi)
    #pragma unroll
    for (int ni = 0; ni < 2; ++ni) acc[mi][ni] = (f32x4){0.f,0.f,0.f,0.f};

  const int rA = tid >> 3, cA = tid & 7;

  const int nkt = K >> 6;
  for (int kt = 0; kt < nkt; ++kt) {
    const int kbase = kt * 64;
    __syncthreads();
    #pragma unroll
    for (int i = 0; i < 4; ++i) {
      const int idx = tid + i*256;
      const int r = rA + i*32;
      int m = m0 + r; if (m > 59999) m = 59999;
      gload16(Asrc + (size_t)m*K + kbase + ((cA ^ (r & 7)) * 8), &As[idx*8]);
    }
    #pragma unroll
    for (int i = 0; i < 2; ++i) {
      const int idx = tid + i*256;
      const int r = rA + i*32;
      gload16(Bsrc + (size_t)(n0b + r)*K + kbase + ((cA ^ (r & 7)) * 8), &Bs[idx*8]);
    }
    __syncthreads();
    #pragma unroll
    for (int kc = 0; kc < 2; ++kc) {
      const int kchunk = kc*4 + (lane >> 4);
      short8 a[4], b[2];
      #pragma unroll
      for (int mi = 0; mi < 4; ++mi) {
        const int m = wm + mi*16 + (lane & 15);
        a[mi] = *(const short8*)&As[m*64 + ((kchunk ^ (m & 7)) * 8)];
      }
      #pragma unroll
      for (int ni = 0; ni < 2; ++ni) {
        const int r = wn + ni*16 + (lane & 15);
        b[ni] = *(const short8*)&Bs[r*64 + ((kchunk ^ (r & 7)) * 8)];
      }
      #pragma unroll
      for (int mi = 0; mi < 4; ++mi)
        #pragma unroll
        for (int ni = 0; ni < 2; ++ni)
          acc[mi][ni] = __builtin_amdgcn_mfma_f32_16x16x32_bf16(a[mi], b[ni], acc[mi][ni], 0, 0, 0);
    }
  }

  const int mrow = (lane >> 4) * 4;
  #pragma unroll
  for (int mi = 0; mi < 4; ++mi) {
    const int mb = m0 + wm + mi*16 + mrow;
    if (mb >= 60000) continue;
    #pragma unroll
    for (int ni = 0; ni < 2; ++ni) {
      const int co = n0b + wn + ni*16 + (lane & 15);
      uint2 pk;
      pk.x = cvt_pk_bf16(acc[mi][ni][0], acc[mi][ni][1]);
      pk.y = cvt_pk_bf16(acc[mi][ni][2], acc[mi][ni][3]);
      *(uint2*)&Cb[(size_t)co*60000 + mb] = pk;
    }
  }
}

// ---------- bf16 MFMA GEMM, 128x256 tile, 512 thr (N=256: A read once) ----------
__global__ __launch_bounds__(512) void k_gemm2(const u16* __restrict__ Asrc,
    const u16* __restrict__ Bsrc, u16* __restrict__ Cb, int K) {
  const int m0 = blockIdx.x * 128;
  const int tid = threadIdx.x;
  const int lane = tid & 63, wid = tid >> 6;
  const int wm = (wid >> 2) * 64, wn = (wid & 3) * 64;

  __shared__ u16 As[128*64];
  __shared__ u16 Bs[256*64];

  f32x4 acc[4][4];
  #pragma unroll
  for (int mi = 0; mi < 4; ++mi)
    #pragma unroll
    for (int ni = 0; ni < 4; ++ni) acc[mi][ni] = (f32x4){0.f,0.f,0.f,0.f};

  const int rA = tid >> 3, cA = tid & 7;

  const int nkt = K >> 6;
  for (int kt = 0; kt < nkt; ++kt) {
    const int kbase = kt * 64;
    __syncthreads();
    #pragma unroll
    for (int i = 0; i < 2; ++i) {
      const int idx = tid + i*512;
      const int r = rA + i*64;
      int m = m0 + r; if (m > 59999) m = 59999;
      gload16(Asrc + (size_t)m*K + kbase + ((cA ^ (r & 7)) * 8), &As[idx*8]);
    }
    #pragma unroll
    for (int i = 0; i < 4; ++i) {
      const int idx = tid + i*512;
      const int r = rA + i*64;
      gload16(Bsrc + (size_t)r*K + kbase + ((cA ^ (r & 7)) * 8), &Bs[idx*8]);
    }
    __syncthreads();
    #pragma unroll
    for (int kc = 0; kc < 2; ++kc) {
      const int kchunk = kc*4 + (lane >> 4);
      short8 a[4], b[4];
      #pragma unroll
      for (int mi = 0; mi < 4; ++mi) {
        const int m = wm + mi*16 + (lane & 15);
        a[mi] = *(const short8*)&As[m*64 + ((kchunk ^ (m & 7)) * 8)];
      }
      #pragma unroll
      for (int ni = 0; ni < 4; ++ni) {
        const int r = wn + ni*16 + (lane & 15);
        b[ni] = *(const short8*)&Bs[r*64 + ((kchunk ^ (r & 7)) * 8)];
      }
      #pragma unroll
      for (int mi = 0; mi < 4; ++mi)
        #pragma unroll
        for (int ni = 0; ni < 4; ++ni)
          acc[mi][ni] = __builtin_amdgcn_mfma_f32_16x16x32_bf16(a[mi], b[ni], acc[mi][ni], 0, 0, 0);
    }
  }

  const int mrow = (lane >> 4) * 4;
  #pragma unroll
  for (int mi = 0; mi < 4; ++mi) {
    const int mb = m0 + wm + mi*16 + mrow;
    if (mb >= 60000) continue;
    #pragma unroll
    for (int ni = 0; ni < 4; ++ni) {
      const int co = wn + ni*16 + (lane & 15);
      uint2 pk;
      pk.x = cvt_pk_bf16(acc[mi][ni][0], acc[mi][ni][1]);
      pk.y = cvt_pk_bf16(acc[mi][ni][2], acc[mi][ni][3]);
      *(uint2*)&Cb[(size_t)co*60000 + mb] = pk;
    }
  }
}

// ---------- BN partial stats of windowed sum S (bf16 Z [co][60000]), per (c,n) ----------
__global__ __launch_bounds__(256) void k_bn_part_win(const u16* __restrict__ G,
    float* __restrict__ part, int cout) {
  const int c = blockIdx.x, n = blockIdx.y;
  const int tid = threadIdx.x;
  const u16* gb = G + (size_t)c*60000 + (size_t)n*7500;
  float s = 0.f, q = 0.f;
  for (int i = tid; i < 7500; i += 256) {
    const int ss = i / 25, w = i % 25;
    float S = 0.f;
    if (ss >= 8) {
      #pragma unroll
      for (int d = 0; d < 9; ++d) S += bf2f(gb[i - d*25]);
    } else {
      for (int tt = 0; tt <= ss; ++tt) S += bf2f(gb[tt*25 + w]);
    }
    s += S; q += S*S;
  }
  __shared__ float rs[256], rq[256];
  rs[tid] = s; rq[tid] = q;
  __syncthreads();
  for (int off = 128; off > 0; off >>= 1) {
    if (tid < off) { rs[tid] += rs[tid+off]; rq[tid] += rq[tid+off]; }
    __syncthreads();
  }
  if (tid == 0) {
    part[((size_t)c*8 + n)*2]     = rs[0];
    part[((size_t)c*8 + n)*2 + 1] = rq[0];
  }
}

// ---------- BN partial stats, plain (bf16 R [co][60000]) ----------
__global__ __launch_bounds__(256) void k_bn_part_plain(const u16* __restrict__ R,
    float* __restrict__ part, int cout) {
  const int c = blockIdx.x, n = blockIdx.y;
  const int tid = threadIdx.x;
  const u16* rb = R + (size_t)c*60000 + (size_t)n*7500;
  float s = 0.f, q = 0.f;
  for (int i = tid; i < 7500; i += 256) {
    const float val = bf2f(rb[i]);
    s += val; q += val*val;
  }
  __shared__ float rs[256], rq[256];
  rs[tid] = s; rq[tid] = q;
  __syncthreads();
  for (int off = 128; off > 0; off >>= 1) {
    if (tid < off) { rs[tid] += rs[tid+off]; rq[tid] += rq[tid+off]; }
    __syncthreads();
  }
  if (tid == 0) {
    part[((size_t)c*8 + n)*2]     = rs[0];
    part[((size_t)c*8 + n)*2 + 1] = rq[0];
  }
}

// ---------- fused BN-finalize + window-sum + BN + relu + residual ----------
__global__ __launch_bounds__(256) void k_apply2(const u16* __restrict__ G,
    const u16* __restrict__ Rb, const u16* Hres,
    const float* __restrict__ part, const float* __restrict__ g, const float* __restrict__ b,
    const float* __restrict__ rpart, const float* __restrict__ rg, const float* __restrict__ rbb,
    u16* Out, int cout, int mode) {
  const int bc = blockIdx.x;          // n*cout + c
  const int c = bc % cout, n = bc / cout;
  float s = 0.f, q = 0.f;
  #pragma unroll
  for (int i = 0; i < 8; ++i) {
    s += part[((size_t)c*8 + i)*2];
    q += part[((size_t)c*8 + i)*2 + 1];
  }
  const float mean = s / 60000.f;
  const float var  = q / 60000.f - mean*mean;
  const float sc = g[c] * rsqrtf(var + EPS);
  const float sh = b[c] - mean*sc;
  float rsc = 0.f, rsh = 0.f;
  if (mode == 1) {
    float s2 = 0.f, q2 = 0.f;
    #pragma unroll
    for (int i = 0; i < 8; ++i) {
      s2 += rpart[((size_t)c*8 + i)*2];
      q2 += rpart[((size_t)c*8 + i)*2 + 1];
    }
    const float m2 = s2 / 60000.f;
    const float v2 = q2 / 60000.f - m2*m2;
    rsc = rg[c] * rsqrtf(v2 + EPS);
    rsh = rbb[c] - m2*rsc;
  }
  const u16* gb = G + (size_t)c*60000 + (size_t)n*7500;
  const size_t rbase = (size_t)c*60000 + (size_t)n*7500;
  for (int i = threadIdx.x; i < 7500; i += 256) {
    const int ss = i / 25, w = i % 25;
    float S = 0.f;
    if (ss >= 8) {
      #pragma unroll
      for (int d = 0; d < 9; ++d) S += bf2f(gb[i - d*25]);
    } else {
      for (int tt = 0; tt <= ss; ++tt) S += bf2f(gb[tt*25 + w]);
    }
    const float h = fmaxf(S*sc + sh, 0.f);
    float o;
    if (mode == 0)      o = h;
    else if (mode == 1) o = fmaxf(h + (bf2f(Rb[rbase + i])*rsc + rsh), 0.f);
    else                o = fmaxf(h + bf2f(Hres[(size_t)bc*7500 + i]), 0.f);
    Out[(size_t)bc*7500 + i] = f2bf(o);
  }
}

// ---------- mean pool over joints, TRANSPOSED output HPt[n][t][c] ----------
__global__ __launch_bounds__(256) void k_poolt(const u16* __restrict__ H,
    float* __restrict__ HPt) {
  const int n = blockIdx.y, t0 = blockIdx.x * 30;
  const int c = threadIdx.x;
  __shared__ float tile[256][31];
  const u16* src = &H[((size_t)(n*256 + c)*300 + t0)*25];
  for (int tt = 0; tt < 30; ++tt) {
    float s = 0.f;
    #pragma unroll
    for (int v = 0; v < 25; ++v) s += bf2f(src[tt*25 + v]);
    tile[c][tt] = s * 0.04f;
  }
  __syncthreads();
  for (int i = threadIdx.x; i < 30*256; i += 256) {
    const int tt = i >> 8, cc = i & 255;
    HPt[((size_t)n*300 + t0 + tt)*256 + cc] = tile[cc][tt];
  }
}

// ---------- classifier conv v2: one t per block, 4 lanes per output ----------
__global__ __launch_bounds__(256) void k_fout2(const float* __restrict__ HPt,
    const float* __restrict__ fW, const float* __restrict__ fb,
    float* __restrict__ out) {
  const int t = blockIdx.x, n = blockIdx.y;
  const int tid = threadIdx.x;
  __shared__ float hp[256];
  hp[tid] = HPt[((size_t)n*300 + t)*256 + tid];
  __syncthreads();
  const int o = tid >> 2, kq = tid & 3;
  float s = 0.f;
  if (o < 60) {
    const float* wrow = fW + o*256 + kq*64;
    const float* hrow = hp + kq*64;
    #pragma unroll
    for (int c = 0; c < 64; c += 4) {
      const f32x4 w4 = *(const f32x4*)&wrow[c];
      const f32x4 h4 = *(const f32x4*)&hrow[c];
      s += w4[0]*h4[0] + w4[1]*h4[1] + w4[2]*h4[2] + w4[3]*h4[3];
    }
  }
  s += __shfl_xor(s, 1);
  s += __shfl_xor(s, 2);
  if (o < 60 && kq == 0)
    out[((size_t)n*60 + o)*300 + t] = s + fb[o];
}

extern "C" void kernel_launch(void* const* d_in, const int* in_sizes, int n_in,
                              void* d_out, int out_size, void* d_ws, size_t ws_size,
                              hipStream_t stream) {
  (void)in_sizes; (void)n_in; (void)out_size; (void)ws_size;
  const float* x     = (const float*)d_in[0];
  const float* A     = (const float*)d_in[1];
  const float* bng   = (const float*)d_in[2];
  const float* bnb   = (const float*)d_in[3];
  const float* finW  = (const float*)d_in[4];
  const float* finb  = (const float*)d_in[5];
  const float* imp0  = (const float*)d_in[6];
  const float* imp1  = (const float*)d_in[7];
  const float* imp2  = (const float*)d_in[8];
  const float* imp3  = (const float*)d_in[9];
  const float* W0    = (const float*)d_in[10];
  const float* g0    = (const float*)d_in[11];
  const float* b0    = (const float*)d_in[12];
  const float* W1    = (const float*)d_in[13];
  const float* g1    = (const float*)d_in[14];
  const float* b1    = (const float*)d_in[15];
  const float* Wr1   = (const float*)d_in[16];
  const float* gr1   = (const float*)d_in[17];
  const float* br1   = (const float*)d_in[18];
  const float* W2    = (const float*)d_in[19];
  const float* g2    = (const float*)d_in[20];
  const float* b2    = (const float*)d_in[21];
  const float* Wr2   = (const float*)d_in[22];
  const float* gr2   = (const float*)d_in[23];
  const float* br2   = (const float*)d_in[24];
  const float* W3    = (const float*)d_in[25];
  const float* g3    = (const float*)d_in[26];
  const float* b3    = (const float*)d_in[27];
  const float* foutW = (const float*)d_in[28];
  const float* foutb = (const float*)d_in[29];
  float* out = (float*)d_out;

  char* base = (char*)d_ws;
  u16*   Z    = (u16*)base;                        // bf16 [co][60000] (<=30.72 MB)
  u16*   Hmk  = (u16*)base;                        // overlay (dead before Z written)
  float* HPt  = (float*)(base + 40000000);         // fp32 [n][t][c] (2.46 MB)
  float* PART = (float*)(base + 45000000);
  float* RPART= (float*)(base + 45100000);
  u16*   XA   = (u16*)(base + 61440000);           // bf16 [60000][K], up to 92.16 MB
  u16*   Rb   = (u16*)(base + 107520000);          // bf16 [co][60000] (layers 1,2 only)
  u16*   Hct  = (u16*)(base + 153600000);          // bf16 [n][c][t][v], 30.72 MB
  u16*   HPAD = (u16*)(base + 184320000);          // 64B zero pad (xa_mfma overhang)
  u16*   ATb  = (u16*)(base + 185000000);          // bf16 [4][3][32][32]
  u16*   WT   = (u16*)(base + 186777600);
  float* ST   = (float*)(base + 188000000);
  float* ISC = ST, *ISH = ST + 80;

  u16* W0t  = WT;            // 64 x 192
  u16* W1t  = WT + 12288;    // 128 x 192
  u16* Wr1t = WT + 36864;    // 128 x 64
  u16* W2t  = WT + 45056;    // 256 x 384
  u16* Wr2t = WT + 143360;   // 256 x 128
  u16* W3t  = WT + 176128;   // 256 x 768

  // ---- prep (single kernel) ----
  k_prep_all<<<1505, 256, 0, stream>>>(A, imp0, imp1, imp2, imp3,
      W0, W1, Wr1, W2, Wr2, W3, W0t, W1t, Wr1t, W2t, Wr2t, W3t, ATb, HPAD);

  k_bn_in_stats<<<75, 256, 0, stream>>>(x, bng, bnb, ISC, ISH);
  k_fin<<<dim3(30, 8), 256, 0, stream>>>(x, ISC, ISH, finW, finb, Hct);

  const int MT = 469;   // ceil(60000/128)
  const int ldsK192 = 25 * (192 + 8) * 2;   // 10.0 KB
  const int ldsK384 = 25 * (384 + 8) * 2;   // 19.6 KB
  const int ldsK768 = 25 * (768 + 8) * 2;   // 38.8 KB

  // ---- layer 0: 64 -> 64 (MFMA xa v5) ----
  k_xa_mfma5<64><<<dim3(150, 8), 256, ldsK192, stream>>>(Hct, ATb, XA);
  k_gemm<<<dim3(1, MT), 256, 0, stream>>>(XA, W0t, Z, 192);
  k_bn_part_win<<<dim3(64, 8), 256, 0, stream>>>(Z, PART, 64);
  k_apply2<<<8*64, 256, 0, stream>>>(Z, nullptr, nullptr, PART, g0, b0,
      nullptr, nullptr, nullptr, Hct, 64, 0);

  // ---- layer 1: 64 -> 128 (MFMA xa v5 + hmk transpose) ----
  k_hmk<<<dim3(118, 2, 8), 256, 0, stream>>>(Hct, Hmk, 64);
  k_xa_mfma5<64><<<dim3(150, 8), 256, ldsK192, stream>>>(Hct, ATb + 1*3072, XA);
  k_gemm<<<dim3(2, MT), 256, 0, stream>>>(Hmk, Wr1t, Rb, 64);
  k_bn_part_plain<<<dim3(128, 8), 256, 0, stream>>>(Rb, RPART, 128);
  k_gemm<<<dim3(2, MT), 256, 0, stream>>>(XA, W1t, Z, 192);
  k_bn_part_win<<<dim3(128, 8), 256, 0, stream>>>(Z, PART, 128);
  k_apply2<<<8*128, 256, 0, stream>>>(Z, Rb, nullptr, PART, g1, b1,
      RPART, gr1, br1, Hct, 128, 1);

  // ---- layer 2: 128 -> 256 (MFMA xa v5 + hmk transpose; N=256 gemms) ----
  k_hmk<<<dim3(118, 4, 8), 256, 0, stream>>>(Hct, Hmk, 128);
  k_xa_mfma5<128><<<dim3(150, 8), 256, ldsK384, stream>>>(Hct, ATb + 2*3072, XA);
  k_gemm2<<<MT, 512, 0, stream>>>(Hmk, Wr2t, Rb, 128);
  k_bn_part_plain<<<dim3(256, 8), 256, 0, stream>>>(Rb, RPART, 256);
  k_gemm2<<<MT, 512, 0, stream>>>(XA, W2t, Z, 384);
  k_bn_part_win<<<dim3(256, 8), 256, 0, stream>>>(Z, PART, 256);
  k_apply2<<<8*256, 256, 0, stream>>>(Z, Rb, nullptr, PART, g2, b2,
      RPART, gr2, br2, Hct, 256, 1);

  // ---- layer 3: 256 -> 256, identity residual (MFMA xa v5, N=256 gemm) ----
  k_xa_mfma5<256><<<dim3(150, 8), 256, ldsK768, stream>>>(Hct, ATb + 3*3072, XA);
  k_gemm2<<<MT, 512, 0, stream>>>(XA, W3t, Z, 768);
  k_bn_part_win<<<dim3(256, 8), 256, 0, stream>>>(Z, PART, 256);
  k_apply2<<<8*256, 256, 0, stream>>>(Z, nullptr, Hct, PART, g3, b3,
      nullptr, nullptr, nullptr, Hct, 256, 2);

  // ---- head ----
  k_poolt<<<dim3(10, 8), 256, 0, stream>>>(Hct, HPt);
  k_fout2<<<dim3(300, 8), 256, 0, stream>>>(HPt, foutW, foutb, out);
}

// Round 13
// 424.752 us; speedup vs baseline: 1.0449x; 1.0449x over previous
//
#include <hip/hip_runtime.h>

#define EPS 1e-5f
typedef unsigned short u16;
typedef __attribute__((ext_vector_type(8))) short short8;
typedef __attribute__((ext_vector_type(4))) float f32x4;

__device__ __forceinline__ float bf2f(u16 u) {
  union { unsigned int i; float f; } c; c.i = ((unsigned int)u) << 16; return c.f;
}
__device__ __forceinline__ u16 f2bf(float f) {
  union { float f; unsigned int i; } c; c.f = f;
  unsigned int u = c.i;
  u += 0x7fffu + ((u >> 16) & 1u);   // round-to-nearest-even
  return (u16)(u >> 16);
}
__device__ __forceinline__ unsigned int cvt_pk_bf16(float lo, float hi) {
  unsigned int r;
  asm("v_cvt_pk_bf16_f32 %0, %1, %2" : "=v"(r) : "v"(lo), "v"(hi));
  return r;
}
// unaligned-safe 16B load (H rows are 50B-strided)
__device__ __forceinline__ short8 load8u(const u16* p) {
  short8 v; __builtin_memcpy(&v, p, 16); return v;
}
// async global->LDS, 16B per lane; dest = wave-uniform base + lane*16 (linear)
__device__ __forceinline__ void gload16(const u16* g, u16* l) {
  __builtin_amdgcn_global_load_lds(
      (__attribute__((address_space(1))) void*)(void*)g,
      (__attribute__((address_space(3))) void*)l, 16, 0, 0);
}

// ---------- merged prep: 6 weight transposes, ATb, Hct end-pad ----------
__device__ __forceinline__ void prep_w_elem(const float* W, u16* Wt,
    int cin, int cout, int P, int idx) {
  const int K = P*cin;
  const int co = idx / K, k = idx % K;
  const int p = k / cin, ci = k % cin;
  Wt[idx] = f2bf(W[((size_t)(p*cout + co))*cin + ci]);
}

__global__ __launch_bounds__(256) void k_prep_all(
    const float* __restrict__ A,
    const float* __restrict__ i0, const float* __restrict__ i1,
    const float* __restrict__ i2, const float* __restrict__ i3,
    const float* __restrict__ W0, const float* __restrict__ W1,
    const float* __restrict__ Wr1, const float* __restrict__ W2,
    const float* __restrict__ Wr2, const float* __restrict__ W3,
    u16* W0t, u16* W1t, u16* Wr1t, u16* W2t,
    u16* Wr2t, u16* W3t, u16* ATb, u16* hpad) {
  int idx = blockIdx.x*256 + threadIdx.x;
  if (idx < 12288) { prep_w_elem(W0,  W0t,  64,  64,  3, idx); return; }
  idx -= 12288;
  if (idx < 24576) { prep_w_elem(W1,  W1t,  64,  128, 3, idx); return; }
  idx -= 24576;
  if (idx < 8192)  { prep_w_elem(Wr1, Wr1t, 64,  128, 1, idx); return; }
  idx -= 8192;
  if (idx < 98304) { prep_w_elem(W2,  W2t,  128, 256, 3, idx); return; }
  idx -= 98304;
  if (idx < 32768) { prep_w_elem(Wr2, Wr2t, 128, 256, 1, idx); return; }
  idx -= 32768;
  if (idx < 196608){ prep_w_elem(W3,  W3t,  256, 256, 3, idx); return; }
  idx -= 196608;
  if (idx < 12288) {                     // ATb[l][p][w(32)][v(32)] = bf16(A'[p][v][w]), zero-padded
    const int l = idx / 3072, r = idx % 3072;
    const int p = r / 1024, wv = r % 1024;
    const int w = wv >> 5, v = wv & 31;
    float val = 0.f;
    if (w < 25 && v < 25) {
      const float* imp = (l==0)?i0:(l==1)?i1:(l==2)?i2:i3;
      val = A[(p*25 + v)*25 + w] * imp[v*25 + w];
    }
    ATb[idx] = f2bf(val);
    return;
  }
  idx -= 12288;
  if (idx < 32) hpad[idx] = 0;           // safe overhang for xa_mfma A-frags
}

// ---------- input BN stats: per j = v*3+c over (n,t) ----------
__global__ __launch_bounds__(256) void k_bn_in_stats(const float* __restrict__ x,
    const float* __restrict__ g, const float* __restrict__ b,
    float* __restrict__ iscale, float* __restrict__ ishift) {
  const int j = blockIdx.x;            // 0..74
  const int c = j % 3, v = j / 3;
  const int tid = threadIdx.x;
  float s = 0.f, q = 0.f;
  for (int i = tid; i < 2400; i += 256) {
    const int n = i / 300, t = i % 300;
    const float val = x[(((size_t)n*3 + c)*300 + t)*25 + v];
    s += val; q += val*val;
  }
  __shared__ float rs[256], rq[256];
  rs[tid] = s; rq[tid] = q;
  __syncthreads();
  for (int off = 128; off > 0; off >>= 1) {
    if (tid < off) { rs[tid] += rs[tid+off]; rq[tid] += rq[tid+off]; }
    __syncthreads();
  }
  if (tid == 0) {
    const float mean = rs[0] / 2400.f;
    const float var  = rq[0] / 2400.f - mean*mean;
    const float sc = g[j] * rsqrtf(var + EPS);
    iscale[j] = sc;
    ishift[j] = b[j] - mean*sc;
  }
}

// ---------- fused input-BN apply + fin (3 -> 64), writes bf16 H_ct ----------
__global__ __launch_bounds__(256) void k_fin(const float* __restrict__ x,
    const float* __restrict__ iscale, const float* __restrict__ ishift,
    const float* __restrict__ fW, const float* __restrict__ fb,
    u16* __restrict__ H) {
  const int n = blockIdx.y;
  const int t0 = blockIdx.x * 10;
  const int tid = threadIdx.x;
  __shared__ float xn[3][250];
  __shared__ float wsh[64][3];
  __shared__ float bsh[64];
  if (tid < 192) wsh[tid/3][tid%3] = fW[tid];
  if (tid < 64)  bsh[tid] = fb[tid];
  for (int i = tid; i < 750; i += 256) {
    const int c = i / 250, pos = i % 250;
    const int t = t0 + pos/25, v = pos%25;
    const int j = v*3 + c;
    xn[c][pos] = x[(((size_t)n*3 + c)*300 + t)*25 + v] * iscale[j] + ishift[j];
  }
  __syncthreads();
  for (int e = tid; e < 64*250; e += 256) {
    const int o = e / 250, pos = e % 250;
    float acc = bsh[o]
              + xn[0][pos]*wsh[o][0] + xn[1][pos]*wsh[o][1] + xn[2][pos]*wsh[o][2];
    const int t = t0 + pos/25, v = pos%25;
    H[(((size_t)n*64 + o)*300 + t)*25 + v] = f2bf(acc);
  }
}

// ---------- Hmk transpose: Hmk[(n*7500+m)][ci] = H[n][ci][m] ----------
__global__ __launch_bounds__(256) void k_hmk(const u16* __restrict__ H,
    u16* __restrict__ Hmk, int cin) {
  const int m0  = blockIdx.x * 64;
  const int ci0 = blockIdx.y * 32;
  const int n   = blockIdx.z;
  __shared__ u16 tile[32][72];
  const int tid = threadIdx.x;
  {
    const int ci = tid >> 3, chunk = tid & 7;
    const int m = m0 + chunk * 8;
    const u16* src = &H[(size_t)(n*cin + ci0 + ci)*7500];
    short8 v;
    if (m + 7 < 7500) {
      v = load8u(&src[m]);
    } else {
      #pragma unroll
      for (int j = 0; j < 8; ++j)
        ((u16*)&v)[j] = (m + j < 7500) ? src[m + j] : (u16)0;
    }
    *(short8*)&tile[ci][chunk*8] = v;
  }
  __syncthreads();
  const int mr = tid >> 2, cq = (tid & 3) * 8;
  const int m = m0 + mr;
  if (m < 7500) {
    short8 v;
    #pragma unroll
    for (int j = 0; j < 8; ++j) ((u16*)&v)[j] = tile[cq + j][mr];
    *(short8*)&Hmk[((size_t)n*7500 + m)*cin + ci0 + cq] = v;
  }
}

// ---------- xa via MFMA v5: r8 operand order (packed b64 LDS writes), ----------
// 2 timesteps sequentially (halved LDS), coalesced copy-out.
template<int CIN>
__global__ __launch_bounds__(256) void k_xa_mfma5(const u16* __restrict__ H,
    const u16* __restrict__ ATl, u16* __restrict__ XA) {
  constexpr int K = 3 * CIN;
  constexpr int ldz = K + 8;
  constexpr int ncit = CIN >> 4;
  constexpr int rowchunks = K >> 3;
  const int t0 = blockIdx.x * 2, n = blockIdx.y;
  const int tid = threadIdx.x, lane = tid & 63, wid = tid >> 6;
  const int lrow = lane & 15, lchunk = lane >> 4;
  extern __shared__ u16 zt[];              // [25][K+8]

  short8 bf[3][2];
  #pragma unroll
  for (int p = 0; p < 3; ++p)
    #pragma unroll
    for (int wt = 0; wt < 2; ++wt)
      bf[p][wt] = *(const short8*)&ATl[(p*32 + wt*16 + lrow)*32 + lchunk*8];

  const int w0 = lrow;                     // D col = lane&15
  const int ciq = lchunk * 4;              // D rows = (lane>>4)*4 + r

  #pragma unroll
  for (int tl = 0; tl < 2; ++tl) {
    const int t = t0 + tl;
    if (tl) __syncthreads();               // previous copy-out complete
    for (int citile = wid; citile < ncit; citile += 4) {
      const int ci = citile*16 + lrow;
      const short8 af = load8u(&H[((size_t)(n*CIN + ci)*300 + t)*25 + lchunk*8]);
      #pragma unroll
      for (int p = 0; p < 3; ++p) {
        #pragma unroll
        for (int wt = 0; wt < 2; ++wt) {
          f32x4 acc = (f32x4){0.f, 0.f, 0.f, 0.f};
          acc = __builtin_amdgcn_mfma_f32_16x16x32_bf16(af, bf[p][wt], acc, 0, 0, 0);
          const int w = wt*16 + w0;
          if (w < 25) {
            uint2 pk;
            pk.x = cvt_pk_bf16(acc[0], acc[1]);
            pk.y = cvt_pk_bf16(acc[2], acc[3]);
            *(uint2*)&zt[w*ldz + p*CIN + citile*16 + ciq] = pk;
          }
        }
      }
    }
    __syncthreads();
    const size_t mbase = ((size_t)n*300 + t)*25;
    for (int i = tid; i < 25*rowchunks; i += 256) {
      const int row = i / rowchunks, c = i % rowchunks;
      *(short8*)&XA[(mbase + row)*K + c*8] = *(const short8*)&zt[row*ldz + c*8];
    }
  }
}

// ---------- bf16 MFMA GEMM, 128x64 tile (N=64/128) ----------
__global__ __launch_bounds__(256) void k_gemm(const u16* __restrict__ Asrc,
    const u16* __restrict__ Bsrc, u16* __restrict__ Cb, int K) {
  const int n0b = blockIdx.x * 64;
  const int m0  = blockIdx.y * 128;
  const int tid = threadIdx.x;
  const int lane = tid & 63, wid = tid >> 6;
  const int wm = (wid & 1) * 64, wn = (wid >> 1) * 32;

  __shared__ u16 As[128*64];
  __shared__ u16 Bs[64*64];

  f32x4 acc[4][2];
  #pragma unroll
  for (int mi = 0; mi < 4; ++mi)
    #pragma unroll
    for (int ni = 0; ni < 2; ++ni) acc[mi][ni] = (f32x4){0.f,0.f,0.f,0.f};

  const int rA = tid >> 3, cA = tid & 7;

  const int nkt = K >> 6;
  for (int kt = 0; kt < nkt; ++kt) {
    const int kbase = kt * 64;
    __syncthreads();
    #pragma unroll
    for (int i = 0; i < 4; ++i) {
      const int idx = tid + i*256;
      const int r = rA + i*32;
      int m = m0 + r; if (m > 59999) m = 59999;
      gload16(Asrc + (size_t)m*K + kbase + ((cA ^ (r & 7)) * 8), &As[idx*8]);
    }
    #pragma unroll
    for (int i = 0; i < 2; ++i) {
      const int idx = tid + i*256;
      const int r = rA + i*32;
      gload16(Bsrc + (size_t)(n0b + r)*K + kbase + ((cA ^ (r & 7)) * 8), &Bs[idx*8]);
    }
    __syncthreads();
    #pragma unroll
    for (int kc = 0; kc < 2; ++kc) {
      const int kchunk = kc*4 + (lane >> 4);
      short8 a[4], b[2];
      #pragma unroll
      for (int mi = 0; mi < 4; ++mi) {
        const int m = wm + mi*16 + (lane & 15);
        a[mi] = *(const short8*)&As[m*64 + ((kchunk ^ (m & 7)) * 8)];
      }
      #pragma unroll
      for (int ni = 0; ni < 2; ++ni) {
        const int r = wn + ni*16 + (lane & 15);
        b[ni] = *(const short8*)&Bs[r*64 + ((kchunk ^ (r & 7)) * 8)];
      }
      #pragma unroll
      for (int mi = 0; mi < 4; ++mi)
        #pragma unroll
        for (int ni = 0; ni < 2; ++ni)
          acc[mi][ni] = __builtin_amdgcn_mfma_f32_16x16x32_bf16(a[mi], b[ni], acc[mi][ni], 0, 0, 0);
    }
  }

  const int mrow = (lane >> 4) * 4;
  #pragma unroll
  for (int mi = 0; mi < 4; ++mi) {
    const int mb = m0 + wm + mi*16 + mrow;
    if (mb >= 60000) continue;
    #pragma unroll
    for (int ni = 0; ni < 2; ++ni) {
      const int co = n0b + wn + ni*16 + (lane & 15);
      uint2 pk;
      pk.x = cvt_pk_bf16(acc[mi][ni][0], acc[mi][ni][1]);
      pk.y = cvt_pk_bf16(acc[mi][ni][2], acc[mi][ni][3]);
      *(uint2*)&Cb[(size_t)co*60000 + mb] = pk;
    }
  }
}

// ---------- bf16 MFMA GEMM, 128x256 tile, 512 thr (N=256: A read once) ----------
__global__ __launch_bounds__(512) void k_gemm2(const u16* __restrict__ Asrc,
    const u16* __restrict__ Bsrc, u16* __restrict__ Cb, int K) {
  const int m0 = blockIdx.x * 128;
  const int tid = threadIdx.x;
  const int lane = tid & 63, wid = tid >> 6;
  const int wm = (wid >> 2) * 64, wn = (wid & 3) * 64;

  __shared__ u16 As[128*64];
  __shared__ u16 Bs[256*64];

  f32x4 acc[4][4];
  #pragma unroll
  for (int mi = 0; mi < 4; ++mi)
    #pragma unroll
    for (int ni = 0; ni < 4; ++ni) acc[mi][ni] = (f32x4){0.f,0.f,0.f,0.f};

  const int rA = tid >> 3, cA = tid & 7;

  const int nkt = K >> 6;
  for (int kt = 0; kt < nkt; ++kt) {
    const int kbase = kt * 64;
    __syncthreads();
    #pragma unroll
    for (int i = 0; i < 2; ++i) {
      const int idx = tid + i*512;
      const int r = rA + i*64;
      int m = m0 + r; if (m > 59999) m = 59999;
      gload16(Asrc + (size_t)m*K + kbase + ((cA ^ (r & 7)) * 8), &As[idx*8]);
    }
    #pragma unroll
    for (int i = 0; i < 4; ++i) {
      const int idx = tid + i*512;
      const int r = rA + i*64;
      gload16(Bsrc + (size_t)r*K + kbase + ((cA ^ (r & 7)) * 8), &Bs[idx*8]);
    }
    __syncthreads();
    #pragma unroll
    for (int kc = 0; kc < 2; ++kc) {
      const int kchunk = kc*4 + (lane >> 4);
      short8 a[4], b[4];
      #pragma unroll
      for (int mi = 0; mi < 4; ++mi) {
        const int m = wm + mi*16 + (lane & 15);
        a[mi] = *(const short8*)&As[m*64 + ((kchunk ^ (m & 7)) * 8)];
      }
      #pragma unroll
      for (int ni = 0; ni < 4; ++ni) {
        const int r = wn + ni*16 + (lane & 15);
        b[ni] = *(const short8*)&Bs[r*64 + ((kchunk ^ (r & 7)) * 8)];
      }
      #pragma unroll
      for (int mi = 0; mi < 4; ++mi)
        #pragma unroll
        for (int ni = 0; ni < 4; ++ni)
          acc[mi][ni] = __builtin_amdgcn_mfma_f32_16x16x32_bf16(a[mi], b[ni], acc[mi][ni], 0, 0, 0);
    }
  }

  const int mrow = (lane >> 4) * 4;
  #pragma unroll
  for (int mi = 0; mi < 4; ++mi) {
    const int mb = m0 + wm + mi*16 + mrow;
    if (mb >= 60000) continue;
    #pragma unroll
    for (int ni = 0; ni < 4; ++ni) {
      const int co = wn + ni*16 + (lane & 15);
      uint2 pk;
      pk.x = cvt_pk_bf16(acc[mi][ni][0], acc[mi][ni][1]);
      pk.y = cvt_pk_bf16(acc[mi][ni][2], acc[mi][ni][3]);
      *(uint2*)&Cb[(size_t)co*60000 + mb] = pk;
    }
  }
}

// ---------- BN partial stats of windowed sum S (bf16 Z [co][60000]), per (c,n) ----------
__global__ __launch_bounds__(256) void k_bn_part_win(const u16* __restrict__ G,
    float* __restrict__ part, int cout) {
  const int c = blockIdx.x, n = blockIdx.y;
  const int tid = threadIdx.x;
  const u16* gb = G + (size_t)c*60000 + (size_t)n*7500;
  float s = 0.f, q = 0.f;
  for (int i = tid; i < 7500; i += 256) {
    const int ss = i / 25, w = i % 25;
    float S = 0.f;
    if (ss >= 8) {
      #pragma unroll
      for (int d = 0; d < 9; ++d) S += bf2f(gb[i - d*25]);
    } else {
      for (int tt = 0; tt <= ss; ++tt) S += bf2f(gb[tt*25 + w]);
    }
    s += S; q += S*S;
  }
  __shared__ float rs[256], rq[256];
  rs[tid] = s; rq[tid] = q;
  __syncthreads();
  for (int off = 128; off > 0; off >>= 1) {
    if (tid < off) { rs[tid] += rs[tid+off]; rq[tid] += rq[tid+off]; }
    __syncthreads();
  }
  if (tid == 0) {
    part[((size_t)c*8 + n)*2]     = rs[0];
    part[((size_t)c*8 + n)*2 + 1] = rq[0];
  }
}

// ---------- BN partial stats, plain (bf16 R [co][60000]) ----------
__global__ __launch_bounds__(256) void k_bn_part_plain(const u16* __restrict__ R,
    float* __restrict__ part, int cout) {
  const int c = blockIdx.x, n = blockIdx.y;
  const int tid = threadIdx.x;
  const u16* rb = R + (size_t)c*60000 + (size_t)n*7500;
  float s = 0.f, q = 0.f;
  for (int i = tid; i < 7500; i += 256) {
    const float val = bf2f(rb[i]);
    s += val; q += val*val;
  }
  __shared__ float rs[256], rq[256];
  rs[tid] = s; rq[tid] = q;
  __syncthreads();
  for (int off = 128; off > 0; off >>= 1) {
    if (tid < off) { rs[tid] += rs[tid+off]; rq[tid] += rq[tid+off]; }
    __syncthreads();
  }
  if (tid == 0) {
    part[((size_t)c*8 + n)*2]     = rs[0];
    part[((size_t)c*8 + n)*2 + 1] = rq[0];
  }
}

// ---------- fused BN-finalize + window-sum + BN + relu + residual (+ mean-pool) ----------
__global__ __launch_bounds__(256) void k_apply2(const u16* __restrict__ G,
    const u16* __restrict__ Rb, const u16* Hres,
    const float* __restrict__ part, const float* __restrict__ g, const float* __restrict__ b,
    const float* __restrict__ rpart, const float* __restrict__ rg, const float* __restrict__ rbb,
    u16* Out, float* HPout, int cout, int mode) {
  const int bc = blockIdx.x;          // n*cout + c
  const int c = bc % cout, n = bc / cout;
  __shared__ u16 os[7500];
  float s = 0.f, q = 0.f;
  #pragma unroll
  for (int i = 0; i < 8; ++i) {
    s += part[((size_t)c*8 + i)*2];
    q += part[((size_t)c*8 + i)*2 + 1];
  }
  const float mean = s / 60000.f;
  const float var  = q / 60000.f - mean*mean;
  const float sc = g[c] * rsqrtf(var + EPS);
  const float sh = b[c] - mean*sc;
  float rsc = 0.f, rsh = 0.f;
  if (mode == 1) {
    float s2 = 0.f, q2 = 0.f;
    #pragma unroll
    for (int i = 0; i < 8; ++i) {
      s2 += rpart[((size_t)c*8 + i)*2];
      q2 += rpart[((size_t)c*8 + i)*2 + 1];
    }
    const float m2 = s2 / 60000.f;
    const float v2 = q2 / 60000.f - m2*m2;
    rsc = rg[c] * rsqrtf(v2 + EPS);
    rsh = rbb[c] - m2*rsc;
  }
  const u16* gb = G + (size_t)c*60000 + (size_t)n*7500;
  const size_t rbase = (size_t)c*60000 + (size_t)n*7500;
  for (int i = threadIdx.x; i < 7500; i += 256) {
    const int ss = i / 25, w = i % 25;
    float S = 0.f;
    if (ss >= 8) {
      #pragma unroll
      for (int d = 0; d < 9; ++d) S += bf2f(gb[i - d*25]);
    } else {
      for (int tt = 0; tt <= ss; ++tt) S += bf2f(gb[tt*25 + w]);
    }
    const float h = fmaxf(S*sc + sh, 0.f);
    float o;
    if (mode == 0)      o = h;
    else if (mode == 1) o = fmaxf(h + (bf2f(Rb[rbase + i])*rsc + rsh), 0.f);
    else                o = fmaxf(h + bf2f(Hres[(size_t)bc*7500 + i]), 0.f);
    const u16 ob = f2bf(o);
    Out[(size_t)bc*7500 + i] = ob;
    if (HPout) os[i] = ob;
  }
  if (HPout) {
    __syncthreads();
    for (int t = threadIdx.x; t < 300; t += 256) {
      float ps = 0.f;
      #pragma unroll
      for (int v = 0; v < 25; ++v) ps += bf2f(os[t*25 + v]);
      HPout[(size_t)bc*300 + t] = ps * 0.04f;
    }
  }
}

// ---------- classifier conv v3: one t per block, HP[n][c][t] (L2-resident) ----------
__global__ __launch_bounds__(256) void k_fout3(const float* __restrict__ HP,
    const float* __restrict__ fW, const float* __restrict__ fb,
    float* __restrict__ out) {
  const int t = blockIdx.x, n = blockIdx.y;
  const int tid = threadIdx.x;
  __shared__ float hp[256];
  hp[tid] = HP[((size_t)n*256 + tid)*300 + t];
  __syncthreads();
  const int o = tid >> 2, kq = tid & 3;
  float s = 0.f;
  if (o < 60) {
    const float* wrow = fW + o*256 + kq*64;
    const float* hrow = hp + kq*64;
    #pragma unroll
    for (int c = 0; c < 64; c += 4) {
      const f32x4 w4 = *(const f32x4*)&wrow[c];
      const f32x4 h4 = *(const f32x4*)&hrow[c];
      s += w4[0]*h4[0] + w4[1]*h4[1] + w4[2]*h4[2] + w4[3]*h4[3];
    }
  }
  s += __shfl_xor(s, 1);
  s += __shfl_xor(s, 2);
  if (o < 60 && kq == 0)
    out[((size_t)n*60 + o)*300 + t] = s + fb[o];
}

extern "C" void kernel_launch(void* const* d_in, const int* in_sizes, int n_in,
                              void* d_out, int out_size, void* d_ws, size_t ws_size,
                              hipStream_t stream) {
  (void)in_sizes; (void)n_in; (void)out_size; (void)ws_size;
  const float* x     = (const float*)d_in[0];
  const float* A     = (const float*)d_in[1];
  const float* bng   = (const float*)d_in[2];
  const float* bnb   = (const float*)d_in[3];
  const float* finW  = (const float*)d_in[4];
  const float* finb  = (const float*)d_in[5];
  const float* imp0  = (const float*)d_in[6];
  const float* imp1  = (const float*)d_in[7];
  const float* imp2  = (const float*)d_in[8];
  const float* imp3  = (const float*)d_in[9];
  const float* W0    = (const float*)d_in[10];
  const float* g0    = (const float*)d_in[11];
  const float* b0    = (const float*)d_in[12];
  const float* W1    = (const float*)d_in[13];
  const float* g1    = (const float*)d_in[14];
  const float* b1    = (const float*)d_in[15];
  const float* Wr1   = (const float*)d_in[16];
  const float* gr1   = (const float*)d_in[17];
  const float* br1   = (const float*)d_in[18];
  const float* W2    = (const float*)d_in[19];
  const float* g2    = (const float*)d_in[20];
  const float* b2    = (const float*)d_in[21];
  const float* Wr2   = (const float*)d_in[22];
  const float* gr2   = (const float*)d_in[23];
  const float* br2   = (const float*)d_in[24];
  const float* W3    = (const float*)d_in[25];
  const float* g3    = (const float*)d_in[26];
  const float* b3    = (const float*)d_in[27];
  const float* foutW = (const float*)d_in[28];
  const float* foutb = (const float*)d_in[29];
  float* out = (float*)d_out;

  char* base = (char*)d_ws;
  u16*   Z    = (u16*)base;                        // bf16 [co][60000] (<=30.72 MB)
  u16*   Hmk  = (u16*)base;                        // overlay (dead before Z written)
  float* HP   = (float*)(base + 40000000);         // fp32 [n][c][t] (2.46 MB)
  float* PART = (float*)(base + 45000000);
  float* RPART= (float*)(base + 45100000);
  u16*   XA   = (u16*)(base + 61440000);           // bf16 [60000][K], up to 92.16 MB
  u16*   Rb   = (u16*)(base + 107520000);          // bf16 [co][60000] (layers 1,2 only)
  u16*   Hct  = (u16*)(base + 153600000);          // bf16 [n][c][t][v], 30.72 MB
  u16*   HPAD = (u16*)(base + 184320000);          // 64B zero pad (xa_mfma overhang)
  u16*   ATb  = (u16*)(base + 185000000);          // bf16 [4][3][32][32]
  u16*   WT   = (u16*)(base + 186777600);
  float* ST   = (float*)(base + 188000000);
  float* ISC = ST, *ISH = ST + 80;

  u16* W0t  = WT;            // 64 x 192
  u16* W1t  = WT + 12288;    // 128 x 192
  u16* Wr1t = WT + 36864;    // 128 x 64
  u16* W2t  = WT + 45056;    // 256 x 384
  u16* Wr2t = WT + 143360;   // 256 x 128
  u16* W3t  = WT + 176128;   // 256 x 768

  // ---- prep (single kernel) ----
  k_prep_all<<<1505, 256, 0, stream>>>(A, imp0, imp1, imp2, imp3,
      W0, W1, Wr1, W2, Wr2, W3, W0t, W1t, Wr1t, W2t, Wr2t, W3t, ATb, HPAD);

  k_bn_in_stats<<<75, 256, 0, stream>>>(x, bng, bnb, ISC, ISH);
  k_fin<<<dim3(30, 8), 256, 0, stream>>>(x, ISC, ISH, finW, finb, Hct);

  const int MT = 469;   // ceil(60000/128)
  const int ldsK192 = 25 * (192 + 8) * 2;   // 10.0 KB
  const int ldsK384 = 25 * (384 + 8) * 2;   // 19.6 KB
  const int ldsK768 = 25 * (768 + 8) * 2;   // 38.8 KB

  // ---- layer 0: 64 -> 64 (MFMA xa v5) ----
  k_xa_mfma5<64><<<dim3(150, 8), 256, ldsK192, stream>>>(Hct, ATb, XA);
  k_gemm<<<dim3(1, MT), 256, 0, stream>>>(XA, W0t, Z, 192);
  k_bn_part_win<<<dim3(64, 8), 256, 0, stream>>>(Z, PART, 64);
  k_apply2<<<8*64, 256, 0, stream>>>(Z, nullptr, nullptr, PART, g0, b0,
      nullptr, nullptr, nullptr, Hct, nullptr, 64, 0);

  // ---- layer 1: 64 -> 128 (MFMA xa v5 + hmk transpose) ----
  k_hmk<<<dim3(118, 2, 8), 256, 0, stream>>>(Hct, Hmk, 64);
  k_xa_mfma5<64><<<dim3(150, 8), 256, ldsK192, stream>>>(Hct, ATb + 1*3072, XA);
  k_gemm<<<dim3(2, MT), 256, 0, stream>>>(Hmk, Wr1t, Rb, 64);
  k_bn_part_plain<<<dim3(128, 8), 256, 0, stream>>>(Rb, RPART, 128);
  k_gemm<<<dim3(2, MT), 256, 0, stream>>>(XA, W1t, Z, 192);
  k_bn_part_win<<<dim3(128, 8), 256, 0, stream>>>(Z, PART, 128);
  k_apply2<<<8*128, 256, 0, stream>>>(Z, Rb, nullptr, PART, g1, b1,
      RPART, gr1, br1, Hct, nullptr, 128, 1);

  // ---- layer 2: 128 -> 256 (MFMA xa v5 + hmk transpose; N=256 gemms) ----
  k_hmk<<<dim3(118, 4, 8), 256, 0, stream>>>(Hct, Hmk, 128);
  k_xa_mfma5<128><<<dim3(150, 8), 256, ldsK384, stream>>>(Hct, ATb + 2*3072, XA);
  k_gemm2<<<MT, 512, 0, stream>>>(Hmk, Wr2t, Rb, 128);
  k_bn_part_plain<<<dim3(256, 8), 256, 0, stream>>>(Rb, RPART, 256);
  k_gemm2<<<MT, 512, 0, stream>>>(XA, W2t, Z, 384);
  k_bn_part_win<<<dim3(256, 8), 256, 0, stream>>>(Z, PART, 256);
  k_apply2<<<8*256, 256, 0, stream>>>(Z, Rb, nullptr, PART, g2, b2,
      RPART, gr2, br2, Hct, nullptr, 256, 1);

  // ---- layer 3: 256 -> 256, identity residual (MFMA xa v5, N=256 gemm) ----
  k_xa_mfma5<256><<<dim3(150, 8), 256, ldsK768, stream>>>(Hct, ATb + 3*3072, XA);
  k_gemm2<<<MT, 512, 0, stream>>>(XA, W3t, Z, 768);
  k_bn_part_win<<<dim3(256, 8), 256, 0, stream>>>(Z, PART, 256);
  k_apply2<<<8*256, 256, 0, stream>>>(Z, nullptr, Hct, PART, g3, b3,
      nullptr, nullptr, nullptr, Hct, HP, 256, 2);

  // ---- head: classifier directly from pooled HP ----
  k_fout3<<<dim3(300, 8), 256, 0, stream>>>(HP, foutW, foutb, out);
}

// Round 15
// 418.911 us; speedup vs baseline: 1.0595x; 1.0139x over previous
//
#include <hip/hip_runtime.h>

#define EPS 1e-5f
typedef unsigned short u16;
typedef __attribute__((ext_vector_type(8))) short short8;
typedef __attribute__((ext_vector_type(4))) float f32x4;

__device__ __forceinline__ float bf2f(u16 u) {
  union { unsigned int i; float f; } c; c.i = ((unsigned int)u) << 16; return c.f;
}
__device__ __forceinline__ u16 f2bf(float f) {
  union { float f; unsigned int i; } c; c.f = f;
  unsigned int u = c.i;
  u += 0x7fffu + ((u >> 16) & 1u);   // round-to-nearest-even
  return (u16)(u >> 16);
}
__device__ __forceinline__ unsigned int cvt_pk_bf16(float lo, float hi) {
  unsigned int r;
  asm("v_cvt_pk_bf16_f32 %0, %1, %2" : "=v"(r) : "v"(lo), "v"(hi));
  return r;
}
// unaligned-safe 16B load (H rows are 50B-strided)
__device__ __forceinline__ short8 load8u(const u16* p) {
  short8 v; __builtin_memcpy(&v, p, 16); return v;
}
// async global->LDS, 16B per lane; dest = wave-uniform base + lane*16 (linear)
__device__ __forceinline__ void gload16(const u16* g, u16* l) {
  __builtin_amdgcn_global_load_lds(
      (__attribute__((address_space(1))) void*)(void*)g,
      (__attribute__((address_space(3))) void*)l, 16, 0, 0);
}

// ---------- merged prep: 6 weight transposes, ATb, Hct end-pad ----------
__device__ __forceinline__ void prep_w_elem(const float* W, u16* Wt,
    int cin, int cout, int P, int idx) {
  const int K = P*cin;
  const int co = idx / K, k = idx % K;
  const int p = k / cin, ci = k % cin;
  Wt[idx] = f2bf(W[((size_t)(p*cout + co))*cin + ci]);
}

__global__ __launch_bounds__(256) void k_prep_all(
    const float* __restrict__ A,
    const float* __restrict__ i0, const float* __restrict__ i1,
    const float* __restrict__ i2, const float* __restrict__ i3,
    const float* __restrict__ W0, const float* __restrict__ W1,
    const float* __restrict__ Wr1, const float* __restrict__ W2,
    const float* __restrict__ Wr2, const float* __restrict__ W3,
    u16* W0t, u16* W1t, u16* Wr1t, u16* W2t,
    u16* Wr2t, u16* W3t, u16* ATb, u16* hpad) {
  int idx = blockIdx.x*256 + threadIdx.x;
  if (idx < 12288) { prep_w_elem(W0,  W0t,  64,  64,  3, idx); return; }
  idx -= 12288;
  if (idx < 24576) { prep_w_elem(W1,  W1t,  64,  128, 3, idx); return; }
  idx -= 24576;
  if (idx < 8192)  { prep_w_elem(Wr1, Wr1t, 64,  128, 1, idx); return; }
  idx -= 8192;
  if (idx < 98304) { prep_w_elem(W2,  W2t,  128, 256, 3, idx); return; }
  idx -= 98304;
  if (idx < 32768) { prep_w_elem(Wr2, Wr2t, 128, 256, 1, idx); return; }
  idx -= 32768;
  if (idx < 196608){ prep_w_elem(W3,  W3t,  256, 256, 3, idx); return; }
  idx -= 196608;
  if (idx < 12288) {                     // ATb[l][p][w(32)][v(32)] = bf16(A'[p][v][w]), zero-padded
    const int l = idx / 3072, r = idx % 3072;
    const int p = r / 1024, wv = r % 1024;
    const int w = wv >> 5, v = wv & 31;
    float val = 0.f;
    if (w < 25 && v < 25) {
      const float* imp = (l==0)?i0:(l==1)?i1:(l==2)?i2:i3;
      val = A[(p*25 + v)*25 + w] * imp[v*25 + w];
    }
    ATb[idx] = f2bf(val);
    return;
  }
  idx -= 12288;
  if (idx < 32) hpad[idx] = 0;           // safe overhang for xa_mfma af-frags
}

// ---------- input BN stats: per j = v*3+c over (n,t) ----------
__global__ __launch_bounds__(256) void k_bn_in_stats(const float* __restrict__ x,
    const float* __restrict__ g, const float* __restrict__ b,
    float* __restrict__ iscale, float* __restrict__ ishift) {
  const int j = blockIdx.x;            // 0..74
  const int c = j % 3, v = j / 3;
  const int tid = threadIdx.x;
  float s = 0.f, q = 0.f;
  for (int i = tid; i < 2400; i += 256) {
    const int n = i / 300, t = i % 300;
    const float val = x[(((size_t)n*3 + c)*300 + t)*25 + v];
    s += val; q += val*val;
  }
  __shared__ float rs[256], rq[256];
  rs[tid] = s; rq[tid] = q;
  __syncthreads();
  for (int off = 128; off > 0; off >>= 1) {
    if (tid < off) { rs[tid] += rs[tid+off]; rq[tid] += rq[tid+off]; }
    __syncthreads();
  }
  if (tid == 0) {
    const float mean = rs[0] / 2400.f;
    const float var  = rq[0] / 2400.f - mean*mean;
    const float sc = g[j] * rsqrtf(var + EPS);
    iscale[j] = sc;
    ishift[j] = b[j] - mean*sc;
  }
}

// ---------- fused input-BN apply + fin (3 -> 64), writes bf16 H_ct ----------
__global__ __launch_bounds__(256) void k_fin(const float* __restrict__ x,
    const float* __restrict__ iscale, const float* __restrict__ ishift,
    const float* __restrict__ fW, const float* __restrict__ fb,
    u16* __restrict__ H) {
  const int n = blockIdx.y;
  const int t0 = blockIdx.x * 10;
  const int tid = threadIdx.x;
  __shared__ float xn[3][250];
  __shared__ float wsh[64][3];
  __shared__ float bsh[64];
  if (tid < 192) wsh[tid/3][tid%3] = fW[tid];
  if (tid < 64)  bsh[tid] = fb[tid];
  for (int i = tid; i < 750; i += 256) {
    const int c = i / 250, pos = i % 250;
    const int t = t0 + pos/25, v = pos%25;
    const int j = v*3 + c;
    xn[c][pos] = x[(((size_t)n*3 + c)*300 + t)*25 + v] * iscale[j] + ishift[j];
  }
  __syncthreads();
  for (int e = tid; e < 64*250; e += 256) {
    const int o = e / 250, pos = e % 250;
    float acc = bsh[o]
              + xn[0][pos]*wsh[o][0] + xn[1][pos]*wsh[o][1] + xn[2][pos]*wsh[o][2];
    const int t = t0 + pos/25, v = pos%25;
    H[(((size_t)n*64 + o)*300 + t)*25 + v] = f2bf(acc);
  }
}

// ---------- Hmk transpose: Hmk[(n*7500+m)][ci] = H[n][ci][m] ----------
__global__ __launch_bounds__(256) void k_hmk(const u16* __restrict__ H,
    u16* __restrict__ Hmk, int cin) {
  const int m0  = blockIdx.x * 64;
  const int ci0 = blockIdx.y * 32;
  const int n   = blockIdx.z;
  __shared__ u16 tile[32][72];
  const int tid = threadIdx.x;
  {
    const int ci = tid >> 3, chunk = tid & 7;
    const int m = m0 + chunk * 8;
    const u16* src = &H[(size_t)(n*cin + ci0 + ci)*7500];
    short8 v;
    if (m + 7 < 7500) {
      v = load8u(&src[m]);
    } else {
      #pragma unroll
      for (int j = 0; j < 8; ++j)
        ((u16*)&v)[j] = (m + j < 7500) ? src[m + j] : (u16)0;
    }
    *(short8*)&tile[ci][chunk*8] = v;
  }
  __syncthreads();
  const int mr = tid >> 2, cq = (tid & 3) * 8;
  const int m = m0 + mr;
  if (m < 7500) {
    short8 v;
    #pragma unroll
    for (int j = 0; j < 8; ++j) ((u16*)&v)[j] = tile[cq + j][mr];
    *(short8*)&Hmk[((size_t)n*7500 + m)*cin + ci0 + cq] = v;
  }
}

// ---------- xa via MFMA v5: r8 operand order (packed b64 LDS writes), ----------
// 2 timesteps sequentially (halved LDS), coalesced copy-out.
template<int CIN>
__global__ __launch_bounds__(256) void k_xa_mfma5(const u16* __restrict__ H,
    const u16* __restrict__ ATl, u16* __restrict__ XA) {
  constexpr int K = 3 * CIN;
  constexpr int ldz = K + 8;
  constexpr int ncit = CIN >> 4;
  constexpr int rowchunks = K >> 3;
  const int t0 = blockIdx.x * 2, n = blockIdx.y;
  const int tid = threadIdx.x, lane = tid & 63, wid = tid >> 6;
  const int lrow = lane & 15, lchunk = lane >> 4;
  extern __shared__ u16 zt[];              // [25][K+8]

  short8 bf[3][2];
  #pragma unroll
  for (int p = 0; p < 3; ++p)
    #pragma unroll
    for (int wt = 0; wt < 2; ++wt)
      bf[p][wt] = *(const short8*)&ATl[(p*32 + wt*16 + lrow)*32 + lchunk*8];

  const int w0 = lrow;                     // D col = lane&15
  const int ciq = lchunk * 4;              // D rows = (lane>>4)*4 + r

  #pragma unroll
  for (int tl = 0; tl < 2; ++tl) {
    const int t = t0 + tl;
    if (tl) __syncthreads();               // previous copy-out complete
    for (int citile = wid; citile < ncit; citile += 4) {
      const int ci = citile*16 + lrow;
      const short8 af = load8u(&H[((size_t)(n*CIN + ci)*300 + t)*25 + lchunk*8]);
      #pragma unroll
      for (int p = 0; p < 3; ++p) {
        #pragma unroll
        for (int wt = 0; wt < 2; ++wt) {
          f32x4 acc = (f32x4){0.f, 0.f, 0.f, 0.f};
          acc = __builtin_amdgcn_mfma_f32_16x16x32_bf16(af, bf[p][wt], acc, 0, 0, 0);
          const int w = wt*16 + w0;
          if (w < 25) {
            uint2 pk;
            pk.x = cvt_pk_bf16(acc[0], acc[1]);
            pk.y = cvt_pk_bf16(acc[2], acc[3]);
            *(uint2*)&zt[w*ldz + p*CIN + citile*16 + ciq] = pk;
          }
        }
      }
    }
    __syncthreads();
    const size_t mbase = ((size_t)n*300 + t)*25;
    for (int i = tid; i < 25*rowchunks; i += 256) {
      const int row = i / rowchunks, c = i % rowchunks;
      *(short8*)&XA[(mbase + row)*K + c*8] = *(const short8*)&zt[row*ldz + c*8];
    }
  }
}

// ---------- bf16 MFMA GEMM, 128xCOUT tile, 512 thr (B read once per block) ----------
// Generalization of the r6-verified COUT=256 k_gemm2 to COUT in {64,128,256}.
template<int COUT>
__global__ __launch_bounds__(512) void k_gemmT(const u16* __restrict__ Asrc,
    const u16* __restrict__ Bsrc, u16* __restrict__ Cb, int K) {
  constexpr int NI = COUT / 64;            // b-frags per wave
  const int m0 = blockIdx.x * 128;
  const int tid = threadIdx.x;
  const int lane = tid & 63, wid = tid >> 6;
  const int wm = (wid >> 2) * 64, wn = (wid & 3) * (COUT / 4);

  __shared__ u16 As[128*64];
  __shared__ u16 Bs[COUT*64];

  f32x4 acc[4][NI];
  #pragma unroll
  for (int mi = 0; mi < 4; ++mi)
    #pragma unroll
    for (int ni = 0; ni < NI; ++ni) acc[mi][ni] = (f32x4){0.f,0.f,0.f,0.f};

  const int rA = tid >> 3, cA = tid & 7;

  const int nkt = K >> 6;
  for (int kt = 0; kt < nkt; ++kt) {
    const int kbase = kt * 64;
    __syncthreads();
    #pragma unroll
    for (int i = 0; i < 2; ++i) {
      const int idx = tid + i*512;
      const int r = rA + i*64;
      int m = m0 + r; if (m > 59999) m = 59999;
      gload16(Asrc + (size_t)m*K + kbase + ((cA ^ (r & 7)) * 8), &As[idx*8]);
    }
    #pragma unroll
    for (int i = 0; i < NI; ++i) {
      const int idx = tid + i*512;
      const int r = rA + i*64;
      gload16(Bsrc + (size_t)r*K + kbase + ((cA ^ (r & 7)) * 8), &Bs[idx*8]);
    }
    __syncthreads();
    #pragma unroll
    for (int kc = 0; kc < 2; ++kc) {
      const int kchunk = kc*4 + (lane >> 4);
      short8 a[4], b[NI];
      #pragma unroll
      for (int mi = 0; mi < 4; ++mi) {
        const int m = wm + mi*16 + (lane & 15);
        a[mi] = *(const short8*)&As[m*64 + ((kchunk ^ (m & 7)) * 8)];
      }
      #pragma unroll
      for (int ni = 0; ni < NI; ++ni) {
        const int r = wn + ni*16 + (lane & 15);
        b[ni] = *(const short8*)&Bs[r*64 + ((kchunk ^ (r & 7)) * 8)];
      }
      #pragma unroll
      for (int mi = 0; mi < 4; ++mi)
        #pragma unroll
        for (int ni = 0; ni < NI; ++ni)
          acc[mi][ni] = __builtin_amdgcn_mfma_f32_16x16x32_bf16(a[mi], b[ni], acc[mi][ni], 0, 0, 0);
    }
  }

  const int mrow = (lane >> 4) * 4;
  #pragma unroll
  for (int mi = 0; mi < 4; ++mi) {
    const int mb = m0 + wm + mi*16 + mrow;
    if (mb >= 60000) continue;
    #pragma unroll
    for (int ni = 0; ni < NI; ++ni) {
      const int co = wn + ni*16 + (lane & 15);
      uint2 pk;
      pk.x = cvt_pk_bf16(acc[mi][ni][0], acc[mi][ni][1]);
      pk.y = cvt_pk_bf16(acc[mi][ni][2], acc[mi][ni][3]);
      *(uint2*)&Cb[(size_t)co*60000 + mb] = pk;
    }
  }
}

// ---------- BN partial stats of windowed sum S (bf16 Z [co][60000]), per (c,n) ----------
__global__ __launch_bounds__(256) void k_bn_part_win(const u16* __restrict__ G,
    float* __restrict__ part, int cout) {
  const int c = blockIdx.x, n = blockIdx.y;
  const int tid = threadIdx.x;
  const u16* gb = G + (size_t)c*60000 + (size_t)n*7500;
  float s = 0.f, q = 0.f;
  for (int i = tid; i < 7500; i += 256) {
    const int ss = i / 25, w = i % 25;
    float S = 0.f;
    if (ss >= 8) {
      #pragma unroll
      for (int d = 0; d < 9; ++d) S += bf2f(gb[i - d*25]);
    } else {
      for (int tt = 0; tt <= ss; ++tt) S += bf2f(gb[tt*25 + w]);
    }
    s += S; q += S*S;
  }
  __shared__ float rs[256], rq[256];
  rs[tid] = s; rq[tid] = q;
  __syncthreads();
  for (int off = 128; off > 0; off >>= 1) {
    if (tid < off) { rs[tid] += rs[tid+off]; rq[tid] += rq[tid+off]; }
    __syncthreads();
  }
  if (tid == 0) {
    part[((size_t)c*8 + n)*2]     = rs[0];
    part[((size_t)c*8 + n)*2 + 1] = rq[0];
  }
}

// ---------- BN partial stats, plain (bf16 R [co][60000]) ----------
__global__ __launch_bounds__(256) void k_bn_part_plain(const u16* __restrict__ R,
    float* __restrict__ part, int cout) {
  const int c = blockIdx.x, n = blockIdx.y;
  const int tid = threadIdx.x;
  const u16* rb = R + (size_t)c*60000 + (size_t)n*7500;
  float s = 0.f, q = 0.f;
  for (int i = tid; i < 7500; i += 256) {
    const float val = bf2f(rb[i]);
    s += val; q += val*val;
  }
  __shared__ float rs[256], rq[256];
  rs[tid] = s; rq[tid] = q;
  __syncthreads();
  for (int off = 128; off > 0; off >>= 1) {
    if (tid < off) { rs[tid] += rs[tid+off]; rq[tid] += rq[tid+off]; }
    __syncthreads();
  }
  if (tid == 0) {
    part[((size_t)c*8 + n)*2]     = rs[0];
    part[((size_t)c*8 + n)*2 + 1] = rq[0];
  }
}

// ---------- fused BN-finalize + window-sum + BN + relu + residual (+ mean-pool) ----------
__global__ __launch_bounds__(256) void k_apply2(const u16* __restrict__ G,
    const u16* __restrict__ Rb, const u16* Hres,
    const float* __restrict__ part, const float* __restrict__ g, const float* __restrict__ b,
    const float* __restrict__ rpart, const float* __restrict__ rg, const float* __restrict__ rbb,
    u16* Out, float* HPout, int cout, int mode) {
  const int bc = blockIdx.x;          // n*cout + c
  const int c = bc % cout, n = bc / cout;
  __shared__ u16 os[7500];
  float s = 0.f, q = 0.f;
  #pragma unroll
  for (int i = 0; i < 8; ++i) {
    s += part[((size_t)c*8 + i)*2];
    q += part[((size_t)c*8 + i)*2 + 1];
  }
  const float mean = s / 60000.f;
  const float var  = q / 60000.f - mean*mean;
  const float sc = g[c] * rsqrtf(var + EPS);
  const float sh = b[c] - mean*sc;
  float rsc = 0.f, rsh = 0.f;
  if (mode == 1) {
    float s2 = 0.f, q2 = 0.f;
    #pragma unroll
    for (int i = 0; i < 8; ++i) {
      s2 += rpart[((size_t)c*8 + i)*2];
      q2 += rpart[((size_t)c*8 + i)*2 + 1];
    }
    const float m2 = s2 / 60000.f;
    const float v2 = q2 / 60000.f - m2*m2;
    rsc = rg[c] * rsqrtf(v2 + EPS);
    rsh = rbb[c] - m2*rsc;
  }
  const u16* gb = G + (size_t)c*60000 + (size_t)n*7500;
  const size_t rbase = (size_t)c*60000 + (size_t)n*7500;
  for (int i = threadIdx.x; i < 7500; i += 256) {
    const int ss = i / 25, w = i % 25;
    float S = 0.f;
    if (ss >= 8) {
      #pragma unroll
      for (int d = 0; d < 9; ++d) S += bf2f(gb[i - d*25]);
    } else {
      for (int tt = 0; tt <= ss; ++tt) S += bf2f(gb[tt*25 + w]);
    }
    const float h = fmaxf(S*sc + sh, 0.f);
    float o;
    if (mode == 0)      o = h;
    else if (mode == 1) o = fmaxf(h + (bf2f(Rb[rbase + i])*rsc + rsh), 0.f);
    else                o = fmaxf(h + bf2f(Hres[(size_t)bc*7500 + i]), 0.f);
    const u16 ob = f2bf(o);
    Out[(size_t)bc*7500 + i] = ob;
    if (HPout) os[i] = ob;
  }
  if (HPout) {
    __syncthreads();
    for (int t = threadIdx.x; t < 300; t += 256) {
      float ps = 0.f;
      #pragma unroll
      for (int v = 0; v < 25; ++v) ps += bf2f(os[t*25 + v]);
      HPout[(size_t)bc*300 + t] = ps * 0.04f;
    }
  }
}

// ---------- classifier conv v3: one t per block, HP[n][c][t] (L2-resident) ----------
__global__ __launch_bounds__(256) void k_fout3(const float* __restrict__ HP,
    const float* __restrict__ fW, const float* __restrict__ fb,
    float* __restrict__ out) {
  const int t = blockIdx.x, n = blockIdx.y;
  const int tid = threadIdx.x;
  __shared__ float hp[256];
  hp[tid] = HP[((size_t)n*256 + tid)*300 + t];
  __syncthreads();
  const int o = tid >> 2, kq = tid & 3;
  float s = 0.f;
  if (o < 60) {
    const float* wrow = fW + o*256 + kq*64;
    const float* hrow = hp + kq*64;
    #pragma unroll
    for (int c = 0; c < 64; c += 4) {
      const f32x4 w4 = *(const f32x4*)&wrow[c];
      const f32x4 h4 = *(const f32x4*)&hrow[c];
      s += w4[0]*h4[0] + w4[1]*h4[1] + w4[2]*h4[2] + w4[3]*h4[3];
    }
  }
  s += __shfl_xor(s, 1);
  s += __shfl_xor(s, 2);
  if (o < 60 && kq == 0)
    out[((size_t)n*60 + o)*300 + t] = s + fb[o];
}

extern "C" void kernel_launch(void* const* d_in, const int* in_sizes, int n_in,
                              void* d_out, int out_size, void* d_ws, size_t ws_size,
                              hipStream_t stream) {
  (void)in_sizes; (void)n_in; (void)out_size; (void)ws_size;
  const float* x     = (const float*)d_in[0];
  const float* A     = (const float*)d_in[1];
  const float* bng   = (const float*)d_in[2];
  const float* bnb   = (const float*)d_in[3];
  const float* finW  = (const float*)d_in[4];
  const float* finb  = (const float*)d_in[5];
  const float* imp0  = (const float*)d_in[6];
  const float* imp1  = (const float*)d_in[7];
  const float* imp2  = (const float*)d_in[8];
  const float* imp3  = (const float*)d_in[9];
  const float* W0    = (const float*)d_in[10];
  const float* g0    = (const float*)d_in[11];
  const float* b0    = (const float*)d_in[12];
  const float* W1    = (const float*)d_in[13];
  const float* g1    = (const float*)d_in[14];
  const float* b1    = (const float*)d_in[15];
  const float* Wr1   = (const float*)d_in[16];
  const float* gr1   = (const float*)d_in[17];
  const float* br1   = (const float*)d_in[18];
  const float* W2    = (const float*)d_in[19];
  const float* g2    = (const float*)d_in[20];
  const float* b2    = (const float*)d_in[21];
  const float* Wr2   = (const float*)d_in[22];
  const float* gr2   = (const float*)d_in[23];
  const float* br2   = (const float*)d_in[24];
  const float* W3    = (const float*)d_in[25];
  const float* g3    = (const float*)d_in[26];
  const float* b3    = (const float*)d_in[27];
  const float* foutW = (const float*)d_in[28];
  const float* foutb = (const float*)d_in[29];
  float* out = (float*)d_out;

  char* base = (char*)d_ws;
  u16*   Z    = (u16*)base;                        // bf16 [co][60000] (<=30.72 MB)
  u16*   Hmk  = (u16*)base;                        // overlay (dead before Z written)
  float* HP   = (float*)(base + 40000000);         // fp32 [n][c][t] (2.46 MB)
  float* PART = (float*)(base + 45000000);
  float* RPART= (float*)(base + 45100000);
  u16*   XA   = (u16*)(base + 61440000);           // bf16 [60000][K], up to 92.16 MB
  u16*   Rb   = (u16*)(base + 107520000);          // bf16 [co][60000] (layers 1,2 only)
  u16*   Hct  = (u16*)(base + 153600000);          // bf16 [n][c][t][v], 30.72 MB
  u16*   HPAD = (u16*)(base + 184320000);          // 64B zero pad (xa_mfma overhang)
  u16*   ATb  = (u16*)(base + 185000000);          // bf16 [4][3][32][32]
  u16*   WT   = (u16*)(base + 186777600);
  float* ST   = (float*)(base + 188000000);
  float* ISC = ST, *ISH = ST + 80;

  u16* W0t  = WT;            // 64 x 192
  u16* W1t  = WT + 12288;    // 128 x 192
  u16* Wr1t = WT + 36864;    // 128 x 64
  u16* W2t  = WT + 45056;    // 256 x 384
  u16* Wr2t = WT + 143360;   // 256 x 128
  u16* W3t  = WT + 176128;   // 256 x 768

  // ---- prep (single kernel) ----
  k_prep_all<<<1505, 256, 0, stream>>>(A, imp0, imp1, imp2, imp3,
      W0, W1, Wr1, W2, Wr2, W3, W0t, W1t, Wr1t, W2t, Wr2t, W3t, ATb, HPAD);

  k_bn_in_stats<<<75, 256, 0, stream>>>(x, bng, bnb, ISC, ISH);
  k_fin<<<dim3(30, 8), 256, 0, stream>>>(x, ISC, ISH, finW, finb, Hct);

  const int MT = 469;   // ceil(60000/128)
  const int ldsK192 = 25 * (192 + 8) * 2;   // 10.0 KB
  const int ldsK384 = 25 * (384 + 8) * 2;   // 19.6 KB
  const int ldsK768 = 25 * (768 + 8) * 2;   // 38.8 KB

  // ---- layer 0: 64 -> 64 (MFMA xa v5) ----
  k_xa_mfma5<64><<<dim3(150, 8), 256, ldsK192, stream>>>(Hct, ATb, XA);
  k_gemmT<64><<<MT, 512, 0, stream>>>(XA, W0t, Z, 192);
  k_bn_part_win<<<dim3(64, 8), 256, 0, stream>>>(Z, PART, 64);
  k_apply2<<<8*64, 256, 0, stream>>>(Z, nullptr, nullptr, PART, g0, b0,
      nullptr, nullptr, nullptr, Hct, nullptr, 64, 0);

  // ---- layer 1: 64 -> 128 (MFMA xa v5 + hmk transpose) ----
  k_hmk<<<dim3(118, 2, 8), 256, 0, stream>>>(Hct, Hmk, 64);
  k_xa_mfma5<64><<<dim3(150, 8), 256, ldsK192, stream>>>(Hct, ATb + 1*3072, XA);
  k_gemmT<128><<<MT, 512, 0, stream>>>(Hmk, Wr1t, Rb, 64);
  k_bn_part_plain<<<dim3(128, 8), 256, 0, stream>>>(Rb, RPART, 128);
  k_gemmT<128><<<MT, 512, 0, stream>>>(XA, W1t, Z, 192);
  k_bn_part_win<<<dim3(128, 8), 256, 0, stream>>>(Z, PART, 128);
  k_apply2<<<8*128, 256, 0, stream>>>(Z, Rb, nullptr, PART, g1, b1,
      RPART, gr1, br1, Hct, nullptr, 128, 1);

  // ---- layer 2: 128 -> 256 (MFMA xa v5 + hmk transpose) ----
  k_hmk<<<dim3(118, 4, 8), 256, 0, stream>>>(Hct, Hmk, 128);
  k_xa_mfma5<128><<<dim3(150, 8), 256, ldsK384, stream>>>(Hct, ATb + 2*3072, XA);
  k_gemmT<256><<<MT, 512, 0, stream>>>(Hmk, Wr2t, Rb, 128);
  k_bn_part_plain<<<dim3(256, 8), 256, 0, stream>>>(Rb, RPART, 256);
  k_gemmT<256><<<MT, 512, 0, stream>>>(XA, W2t, Z, 384);
  k_bn_part_win<<<dim3(256, 8), 256, 0, stream>>>(Z, PART, 256);
  k_apply2<<<8*256, 256, 0, stream>>>(Z, Rb, nullptr, PART, g2, b2,
      RPART, gr2, br2, Hct, nullptr, 256, 1);

  // ---- layer 3: 256 -> 256, identity residual (MFMA xa v5) ----
  k_xa_mfma5<256><<<dim3(150, 8), 256, ldsK768, stream>>>(Hct, ATb + 3*3072, XA);
  k_gemmT<256><<<MT, 512, 0, stream>>>(XA, W3t, Z, 768);
  k_bn_part_win<<<dim3(256, 8), 256, 0, stream>>>(Z, PART, 256);
  k_apply2<<<8*256, 256, 0, stream>>>(Z, nullptr, Hct, PART, g3, b3,
      nullptr, nullptr, nullptr, Hct, HP, 256, 2);

  // ---- head: classifier directly from pooled HP ----
  k_fout3<<<dim3(300, 8), 256, 0, stream>>>(HP, foutW, foutb, out);
}